// Round 6
// baseline (282.586 us; speedup 1.0000x reference)
//
#include <hip/hip_runtime.h>
#include <hip/hip_bf16.h>

#define BATCH   8
#define C_DIM   512
#define HWD     56
#define NPIX    3136   // 56*56
#define PW      14
#define PP      196    // 14*14
#define M_TOT   588    // 3*196
#define BM_ROWS 4704   // 8*588
#define BM_PAD  4736   // padded to 37*128
#define HEADS   8
#define HD      64
#define N_SEQ   3136
#define SM_SCALE 0.125f

// attention LDS geometry
#define KS_STRIDE 68            // shorts per K row
#define KS_ROWS   592           // 588 + 4 zero pad rows
#define VS_STRIDE 596           // shorts per V^T row
#define ATTN_LDS_SHORTS (KS_ROWS * KS_STRIDE + 64 * VS_STRIDE)   // 78400
#define ATTN_LDS_BYTES  (ATTN_LDS_SHORTS * 2)                    // 156800

// GEMM A-tile stride (68 shorts: staging writes & frag reads <=4-way banks)
#define AS_STR 68

typedef __attribute__((ext_vector_type(8))) short bf16x8;
typedef __attribute__((ext_vector_type(4))) short bf16x4;
typedef __attribute__((ext_vector_type(4))) float f32x4;

__device__ __forceinline__ short f2bs(float f) {
    __hip_bfloat16 h = __float2bfloat16(f);
    return *reinterpret_cast<short*>(&h);
}
__device__ __forceinline__ unsigned pkbf(float lo, float hi) {
    __hip_bfloat162 t = __float22bfloat162_rn(make_float2(lo, hi));
    return *reinterpret_cast<unsigned*>(&t);
}

// 16x16x16 bf16 MFMA (K=16): B-operand layout k=quad*4+jj, n=l15 — matches
// the C/D layout of our S^T tiles directly (no transpose needed for PV).
__device__ __forceinline__ f32x4 mfma16(bf16x4 a, bf16x4 b, f32x4 c) {
#if __has_builtin(__builtin_amdgcn_mfma_f32_16x16x16bf16_1k)
    return __builtin_amdgcn_mfma_f32_16x16x16bf16_1k(a, b, c, 0, 0, 0);
#elif __has_builtin(__builtin_amdgcn_mfma_f32_16x16x16_bf16)
    return __builtin_amdgcn_mfma_f32_16x16x16_bf16(a, b, c, 0, 0, 0);
#else
    asm volatile("v_mfma_f32_16x16x16_bf16 %0, %1, %2, %0\n\ts_nop 7\n\ts_nop 1"
                 : "+v"(c) : "v"(a), "v"(b));
    return c;
#endif
}

// async 16B global->LDS copy (m97 pattern, wave-uniform LDS base).
__device__ __forceinline__ void gl_lds16(const void* g, void* l) {
    __builtin_amdgcn_global_load_lds(
        (const __attribute__((address_space(1))) void*)g,
        (__attribute__((address_space(3))) void*)l, 16, 0, 0);
}

// ---------------------------------------------------------------------------
// Kernel A: the three depthwise branches. One block per (b,c) plane.
// ---------------------------------------------------------------------------
__global__ __launch_bounds__(256) void k_branches(
    const float* __restrict__ x,
    const float* __restrict__ w1a, const float* __restrict__ b1a,
    const float* __restrict__ w1b, const float* __restrict__ b1b,
    const float* __restrict__ w2,  const float* __restrict__ b2,
    const float* __restrict__ w3,  const float* __restrict__ b3,
    float* __restrict__ l_pre)
{
    __shared__ float xs[NPIX];
    __shared__ float y1s[HWD * PW];
    __shared__ float pools[PP];
    const int c = blockIdx.x, b = blockIdx.y, tid = threadIdx.x;
    const float* xp = x + ((size_t)(b * C_DIM + c)) * NPIX;
    for (int i = tid; i < NPIX / 4; i += 256)
        ((float4*)xs)[i] = ((const float4*)xp)[i];
    __syncthreads();

    const float wa0 = w1a[c*4+0], wa1 = w1a[c*4+1], wa2 = w1a[c*4+2], wa3 = w1a[c*4+3];
    const float ba = b1a[c];
    for (int i = tid; i < HWD * PW; i += 256) {
        int h = i / PW, w = i % PW;
        const float* r = xs + h * HWD + w * 4;
        float v = ba + r[0]*wa0 + r[1]*wa1 + r[2]*wa2 + r[3]*wa3;
        y1s[i] = fmaxf(v, 0.f);
    }
    if (tid < PP) {
        int h = tid / PW, w = tid % PW;
        float s = 0.f;
        #pragma unroll
        for (int r = 0; r < 4; ++r) {
            const float* rr = xs + (h*4 + r) * HWD + w * 4;
            s += rr[0] + rr[1] + rr[2] + rr[3];
        }
        pools[tid] = s * (1.f / 16.f);
    }
    __syncthreads();

    if (tid < PP) {
        int h = tid / PW, w = tid % PW;
        float* lp = l_pre + ((size_t)(b * C_DIM + c)) * M_TOT;
        float v1 = b1b[c];
        v1 += y1s[(h*4+0)*PW + w] * w1b[c*4+0];
        v1 += y1s[(h*4+1)*PW + w] * w1b[c*4+1];
        v1 += y1s[(h*4+2)*PW + w] * w1b[c*4+2];
        v1 += y1s[(h*4+3)*PW + w] * w1b[c*4+3];
        lp[tid] = fmaxf(v1, 0.f);
        float v2 = b2[c];
        #pragma unroll
        for (int r = 0; r < 4; ++r)
            #pragma unroll
            for (int s2 = 0; s2 < 4; ++s2)
                v2 += xs[(h*4+r)*HWD + w*4 + s2] * w2[c*16 + r*4 + s2];
        lp[PP + tid] = fmaxf(v2, 0.f);
        float v3 = b3[c];
        #pragma unroll
        for (int dh = -1; dh <= 1; ++dh)
            #pragma unroll
            for (int dw = -1; dw <= 1; ++dw) {
                int hh = h + dh, ww = w + dw;
                if (hh >= 0 && hh < PW && ww >= 0 && ww < PW)
                    v3 += pools[hh*PW + ww] * w3[c*9 + (dh+1)*3 + (dw+1)];
            }
        lp[2*PP + tid] = fmaxf(v3, 0.f);
    }
}

// ---------------------------------------------------------------------------
// Kernel B: LayerNorm stats over C for each (b,m).
// ---------------------------------------------------------------------------
__global__ __launch_bounds__(256) void k_stats(
    const float* __restrict__ l_pre, float2* __restrict__ stats)
{
    __shared__ float ssum[4][64];
    __shared__ float ssq[4][64];
    const int tid = threadIdx.x;
    const int ml = tid & 63, cg = tid >> 6;
    const int b = blockIdx.y;
    const int m = blockIdx.x * 64 + ml;
    float s = 0.f, q = 0.f;
    if (m < M_TOT) {
        const float* base = l_pre + ((size_t)b * C_DIM + cg * 128) * M_TOT + m;
        for (int c = 0; c < 128; ++c) {
            float v = base[(size_t)c * M_TOT];
            s += v; q += v * v;
        }
    }
    ssum[cg][ml] = s; ssq[cg][ml] = q;
    __syncthreads();
    if (tid < 64 && blockIdx.x * 64 + tid < M_TOT) {
        float ts = ssum[0][tid] + ssum[1][tid] + ssum[2][tid] + ssum[3][tid];
        float tq = ssq[0][tid] + ssq[1][tid] + ssq[2][tid] + ssq[3][tid];
        float mu = ts * (1.f / 512.f);
        float var = tq * (1.f / 512.f) - mu * mu;
        stats[(size_t)b * M_TOT + blockIdx.x * 64 + tid] =
            make_float2(mu, rsqrtf(var + 1e-5f));
    }
}

// ---------------------------------------------------------------------------
// Kernel W: weights fp32 -> bf16.
// ---------------------------------------------------------------------------
__global__ __launch_bounds__(256) void k_wconv(
    const float* __restrict__ Wq, const float* __restrict__ Wkv,
    short* __restrict__ Wqb, short* __restrict__ Wkvb)
{
    int i = (blockIdx.x * 256 + threadIdx.x) * 4;
    if (i < 262144) {
        float4 v = *(const float4*)(Wq + i);
        short o[4] = {f2bs(v.x), f2bs(v.y), f2bs(v.z), f2bs(v.w)};
        *(short4*)(Wqb + i) = *(short4*)o;
    } else {
        int j = i - 262144;
        float4 v = *(const float4*)(Wkv + j);
        short o[4] = {f2bs(v.x), f2bs(v.y), f2bs(v.z), f2bs(v.w)};
        *(short4*)(Wkvb + j) = *(short4*)o;
    }
}

// ---------------------------------------------------------------------------
// Kernel G0: q GEMM, A staged DIRECTLY from x [B,C,N] fp32 (fused transpose
// + bf16 convert in the staging loop: 8 coalesced dword loads per c-group,
// one b128 LDS write). rows = B*N, cols 512 -> Qb [B,h,N,d].
// ---------------------------------------------------------------------------
__global__ __launch_bounds__(256) void k_gemm_q(
    const float* __restrict__ x, const short* __restrict__ Bw,
    const float* __restrict__ bias, short* __restrict__ Qb)
{
    __shared__ short As[128 * AS_STR];
    __shared__ short Bs[128 * 64];
    const int tid = threadIdx.x;
    const int lane = tid & 63, w = tid >> 6;
    const int l15 = lane & 15, quad = lane >> 4;
    const int wr = w & 1, wc = w >> 1;
    const int row0 = blockIdx.x * 128, col0 = blockIdx.y * 128;
    const int lr8 = lane >> 3, lc8 = (lane & 7) * 8;

    // A-staging identity: row m_loc, c-groups cgb..cgb+3 (x8 c each)
    const int m_loc = tid & 127;
    const int cgb   = (tid >> 7) * 4;
    const int row_gA = row0 + m_loc;
    const int bA = row_gA / N_SEQ;
    const int nA = row_gA - bA * N_SEQ;
    const float* xrow = x + ((size_t)bA * C_DIM) * NPIX + nA;

    f32x4 acc[4][4] = {};

    for (int c0 = 0; c0 < 512; c0 += 64) {
        __syncthreads();
        #pragma unroll
        for (int it = 0; it < 4; ++it) {
            const int cg = cgb + it;
            const float* src = xrow + (size_t)(c0 + cg * 8) * NPIX;
            short ov[8];
            #pragma unroll
            for (int e = 0; e < 8; ++e) ov[e] = f2bs(src[(size_t)e * NPIX]);
            *(float4*)&As[m_loc * AS_STR + cg * 8] = *(const float4*)ov;
            int r = w * 32 + it * 8;
            gl_lds16(Bw + (size_t)(col0 + r + lr8) * 512 + c0 + lc8, &Bs[r * 64]);
        }
        __syncthreads();
        #pragma unroll
        for (int ks = 0; ks < 2; ++ks) {
            bf16x8 af[4], bf[4];
            #pragma unroll
            for (int t = 0; t < 4; ++t) {
                af[t] = *(const bf16x8*)&As[(wr*64 + t*16 + l15)*AS_STR + ks*32 + quad*8];
                bf[t] = *(const bf16x8*)&Bs[(wc*64 + t*16 + l15)*64 + ks*32 + quad*8];
            }
            #pragma unroll
            for (int nt = 0; nt < 4; ++nt)
                #pragma unroll
                for (int mt = 0; mt < 4; ++mt)
                    acc[nt][mt] = __builtin_amdgcn_mfma_f32_16x16x32_bf16(
                        af[nt], bf[mt], acc[nt][mt], 0, 0, 0);
        }
    }

    #pragma unroll
    for (int nt = 0; nt < 4; ++nt) {
        int row_t = row0 + wr * 64 + nt * 16 + quad * 4;
        #pragma unroll
        for (int mt = 0; mt < 4; ++mt) {
            int col = col0 + wc * 64 + mt * 16 + l15;
            float bv = bias[col];
            int h = col >> 6, d = col & 63;
            #pragma unroll
            for (int r = 0; r < 4; ++r) {
                int row_g = row_t + r;
                int b = row_g / N_SEQ;
                int n = row_g - b * N_SEQ;
                Qb[(((size_t)(b * HEADS + h)) * N_SEQ + n) * HD + d] =
                    f2bs(acc[nt][mt][r] + bv);
            }
        }
    }
}

// ---------------------------------------------------------------------------
// Kernel G1: kv GEMM, A staged DIRECTLY from l_pre [B,C,M] fp32 with LN
// fused into the staging loop (stats per row; gamma/beta wave-uniform).
// rows = B*M padded, cols 1024 -> Kb [B,h,M,d] / Vt [B,h,d,M].
// ---------------------------------------------------------------------------
__global__ __launch_bounds__(256) void k_gemm_kv(
    const float* __restrict__ l_pre, const float2* __restrict__ stats,
    const short* __restrict__ Bw, const float* __restrict__ bias,
    const float* __restrict__ gamma, const float* __restrict__ beta,
    short* __restrict__ Kb, short* __restrict__ Vt)
{
    __shared__ short As[128 * AS_STR];
    __shared__ short Bs[128 * 64];
    const int tid = threadIdx.x;
    const int lane = tid & 63, w = tid >> 6;
    const int l15 = lane & 15, quad = lane >> 4;
    const int wr = w & 1, wc = w >> 1;
    const int row0 = blockIdx.x * 128, col0 = blockIdx.y * 128;
    const int lr8 = lane >> 3, lc8 = (lane & 7) * 8;

    const int m_loc = tid & 127;
    const int cgb   = (tid >> 7) * 4;
    const int row_gA = row0 + m_loc;
    const bool rvA = (row_gA < BM_ROWS);
    int bA = 0, mA = 0; float mu = 0.f, rstd = 0.f;
    if (rvA) {
        bA = row_gA / M_TOT; mA = row_gA - bA * M_TOT;
        float2 st = stats[row_gA];
        mu = st.x; rstd = st.y;
    }
    const float* lrow = l_pre + ((size_t)bA * C_DIM) * M_TOT + mA;

    f32x4 acc[4][4] = {};

    for (int c0 = 0; c0 < 512; c0 += 64) {
        __syncthreads();
        #pragma unroll
        for (int it = 0; it < 4; ++it) {
            const int cg = cgb + it;
            short ov[8] = {0, 0, 0, 0, 0, 0, 0, 0};
            if (rvA) {
                const float* src = lrow + (size_t)(c0 + cg * 8) * M_TOT;
                #pragma unroll
                for (int e = 0; e < 8; ++e) {
                    int c = c0 + cg * 8 + e;
                    ov[e] = f2bs((src[(size_t)e * M_TOT] - mu) * rstd * gamma[c] + beta[c]);
                }
            }
            *(float4*)&As[m_loc * AS_STR + cg * 8] = *(const float4*)ov;
            int r = w * 32 + it * 8;
            gl_lds16(Bw + (size_t)(col0 + r + lr8) * 512 + c0 + lc8, &Bs[r * 64]);
        }
        __syncthreads();
        #pragma unroll
        for (int ks = 0; ks < 2; ++ks) {
            bf16x8 af[4], bf[4];
            #pragma unroll
            for (int t = 0; t < 4; ++t) {
                af[t] = *(const bf16x8*)&As[(wr*64 + t*16 + l15)*AS_STR + ks*32 + quad*8];
                bf[t] = *(const bf16x8*)&Bs[(wc*64 + t*16 + l15)*64 + ks*32 + quad*8];
            }
            #pragma unroll
            for (int nt = 0; nt < 4; ++nt)
                #pragma unroll
                for (int mt = 0; mt < 4; ++mt)
                    acc[nt][mt] = __builtin_amdgcn_mfma_f32_16x16x32_bf16(
                        af[nt], bf[mt], acc[nt][mt], 0, 0, 0);
        }
    }

    #pragma unroll
    for (int nt = 0; nt < 4; ++nt) {
        int row_t = row0 + wr * 64 + nt * 16 + quad * 4;
        #pragma unroll
        for (int mt = 0; mt < 4; ++mt) {
            int col = col0 + wc * 64 + mt * 16 + l15;
            float bv = bias[col];
            #pragma unroll
            for (int r = 0; r < 4; ++r) {
                int row_g = row_t + r;
                float v = acc[nt][mt][r] + bv;
                if (row_g < BM_ROWS) {
                    int b = row_g / M_TOT;
                    int m = row_g - b * M_TOT;
                    if (col < 512) {
                        int h = col >> 6, d = col & 63;
                        Kb[(((size_t)(b * HEADS + h)) * M_TOT + m) * HD + d] = f2bs(v);
                    } else {
                        int jj = col - 512, h = jj >> 6, d = jj & 63;
                        Vt[(((size_t)(b * HEADS + h)) * HD + d) * M_TOT + m] = f2bs(v);
                    }
                }
            }
        }
    }
}

// ---------------------------------------------------------------------------
// Kernel E: persistent-KV MFMA attention (unchanged from R5).
// Grid = (4 n-quarters, h, b) = 256 blocks, 1024 threads (16 waves), 1/CU.
// ---------------------------------------------------------------------------
__global__ __launch_bounds__(1024) void k_attn(
    const short* __restrict__ Qb, const short* __restrict__ Kb,
    const short* __restrict__ Vt, float* __restrict__ out)
{
    extern __shared__ short smem[];
    short* Ks = smem;                       // [592][68]
    short* Vs = smem + KS_ROWS * KS_STRIDE; // [64][596]

    const int tid = threadIdx.x;
    const int lane = tid & 63, w = tid >> 6;
    const int l15 = lane & 15, quad = lane >> 4;
    const int q4 = blockIdx.x, h = blockIdx.y, b = blockIdx.z;
    const size_t bh = (size_t)(b * HEADS + h);
    const size_t kbase = bh * M_TOT * HD;          // Kb [B,h,M,d]
    const size_t vbase = bh * (size_t)HD * M_TOT;  // Vt [B,h,d,M]

    for (int i = tid; i < 4704; i += 1024) {
        int row = i >> 3, seg = i & 7;
        *(float4*)&Ks[row * KS_STRIDE + seg * 8] =
            *(const float4*)(Kb + kbase + (size_t)row * 64 + seg * 8);
    }
    if (tid < 256) {
        int r = tid >> 6, cc = tid & 63;
        Ks[(588 + r) * KS_STRIDE + cc] = 0;
    }
    {
        int row = tid >> 4, tg = tid & 15;
        const short* src = Vt + vbase + (size_t)row * M_TOT;
        #pragma unroll 2
        for (int jj = tg; jj < 147; jj += 16)
            *(float2*)&Vs[row * VS_STRIDE + jj * 4] = *(const float2*)(src + jj * 4);
    }
    if (tid < 512) {
        int row = tid >> 3, cc = tid & 7;
        Vs[row * VS_STRIDE + 588 + cc] = 0;
    }
    __syncthreads();   // the ONLY barrier

    for (int ds = w; ds < 25; ds += 16) {
        const bool sbv = (ds < 24);
        const int nA = q4 * 784 + ds * 32 + l15;
        const int nB = sbv ? nA + 16 : nA;

        bf16x8 qfA[2], qfB[2];
        #pragma unroll
        for (int ks = 0; ks < 2; ++ks) {
            qfA[ks] = *(const bf16x8*)(Qb + (bh * N_SEQ + nA) * HD + ks * 32 + quad * 8);
            qfB[ks] = *(const bf16x8*)(Qb + (bh * N_SEQ + nB) * HD + ks * 32 + quad * 8);
        }

        f32x4 oaccA[4] = {}, oaccB[4] = {};
        float rsA = 0.f, rsB = 0.f;

        for (int j0 = 0; j0 < KS_ROWS; j0 += 16) {
            const short* krow = &Ks[(j0 + l15) * KS_STRIDE];
            bf16x8 kf0 = *(const bf16x8*)&krow[quad * 8];
            bf16x8 kf1 = *(const bf16x8*)&krow[32 + quad * 8];

            f32x4 sA = {}, sB = {};
            sA = __builtin_amdgcn_mfma_f32_16x16x32_bf16(kf0, qfA[0], sA, 0, 0, 0);
            sB = __builtin_amdgcn_mfma_f32_16x16x32_bf16(kf0, qfB[0], sB, 0, 0, 0);
            sA = __builtin_amdgcn_mfma_f32_16x16x32_bf16(kf1, qfA[1], sA, 0, 0, 0);
            sB = __builtin_amdgcn_mfma_f32_16x16x32_bf16(kf1, qfB[1], sB, 0, 0, 0);

            const float msk = (j0 == 576 && quad == 3) ? 0.f : 1.f;
            float pA[4], pB[4];
            #pragma unroll
            for (int r = 0; r < 4; ++r) {
                pA[r] = __expf(sA[r] * SM_SCALE);
                pB[r] = __expf(sB[r] * SM_SCALE);
            }
            rsA += (pA[0] + pA[1] + pA[2] + pA[3]) * msk;
            rsB += (pB[0] + pB[1] + pB[2] + pB[3]) * msk;

            unsigned ua[2] = {pkbf(pA[0], pA[1]), pkbf(pA[2], pA[3])};
            unsigned ub[2] = {pkbf(pB[0], pB[1]), pkbf(pB[2], pB[3])};
            bf16x4 pbA, pbB;
            __builtin_memcpy(&pbA, ua, 8);
            __builtin_memcpy(&pbB, ub, 8);

            #pragma unroll
            for (int dt = 0; dt < 4; ++dt) {
                bf16x4 vf = *(const bf16x4*)&Vs[(dt * 16 + l15) * VS_STRIDE + j0 + quad * 4];
                oaccA[dt] = mfma16(vf, pbA, oaccA[dt]);
                oaccB[dt] = mfma16(vf, pbB, oaccB[dt]);
            }
        }

        rsA += __shfl_xor(rsA, 16); rsA += __shfl_xor(rsA, 32);
        rsB += __shfl_xor(rsB, 16); rsB += __shfl_xor(rsB, 32);
        const float invA = 1.f / rsA;
        const float invB = 1.f / rsB;
        float* orowA = out + ((size_t)b * N_SEQ + nA) * C_DIM + h * HD;
        #pragma unroll
        for (int dt = 0; dt < 4; ++dt) {
            float4 o;
            o.x = oaccA[dt][0] * invA; o.y = oaccA[dt][1] * invA;
            o.z = oaccA[dt][2] * invA; o.w = oaccA[dt][3] * invA;
            *(float4*)&orowA[dt * 16 + quad * 4] = o;
        }
        if (sbv) {
            float* orowB = out + ((size_t)b * N_SEQ + nB) * C_DIM + h * HD;
            #pragma unroll
            for (int dt = 0; dt < 4; ++dt) {
                float4 o;
                o.x = oaccB[dt][0] * invB; o.y = oaccB[dt][1] * invB;
                o.z = oaccB[dt][2] * invB; o.w = oaccB[dt][3] * invB;
                *(float4*)&orowB[dt * 16 + quad * 4] = o;
            }
        }
    }
}

// ---------------------------------------------------------------------------
extern "C" void kernel_launch(void* const* d_in, const int* in_sizes, int n_in,
                              void* d_out, int out_size, void* d_ws, size_t ws_size,
                              hipStream_t stream) {
    const float* x     = (const float*)d_in[0];
    const float* Wq    = (const float*)d_in[1];
    const float* bq    = (const float*)d_in[2];
    const float* Wkv   = (const float*)d_in[3];
    const float* bkv   = (const float*)d_in[4];
    const float* w1a   = (const float*)d_in[5];
    const float* b1a   = (const float*)d_in[6];
    const float* w1b   = (const float*)d_in[7];
    const float* b1b   = (const float*)d_in[8];
    const float* w2    = (const float*)d_in[9];
    const float* b2    = (const float*)d_in[10];
    const float* w3    = (const float*)d_in[11];
    const float* b3    = (const float*)d_in[12];
    const float* gamma = (const float*)d_in[13];
    const float* beta  = (const float*)d_in[14];
    float* out = (float*)d_out;

    char* ws = (char*)d_ws;
    float*  l_pre = (float*)ws;                    //  9,633,792 B [B,C,M]
    float2* stats = (float2*)(ws + 9633792);       //     37,632 B
    short*  Wqb   = (short*)(ws + 9671424);        //    524,288 B
    short*  Wkvb  = (short*)(ws + 10195712);       //  1,048,576 B
    short*  Kb    = (short*)(ws + 11244288);       //  4,816,896 B [B,h,M,d]
    short*  Vt    = (short*)(ws + 16061184);       //  4,816,896 B [B,h,d,M]
    short*  Qb    = (short*)(ws + 20878080);       // 25,690,112 B [B,h,N,d]

    hipFuncSetAttribute((const void*)k_attn,
                        hipFuncAttributeMaxDynamicSharedMemorySize,
                        ATTN_LDS_BYTES);

    k_wconv<<<768, 256, 0, stream>>>(Wq, Wkv, Wqb, Wkvb);
    k_gemm_q<<<dim3(196, 4), 256, 0, stream>>>(x, Wqb, bq, Qb);
    k_branches<<<dim3(C_DIM, BATCH), 256, 0, stream>>>(
        x, w1a, b1a, w1b, b1b, w2, b2, w3, b3, l_pre);
    k_stats<<<dim3(10, BATCH), 256, 0, stream>>>(l_pre, stats);
    k_gemm_kv<<<dim3(37, 8), 256, 0, stream>>>(
        l_pre, stats, Wkvb, bkv, gamma, beta, Kb, Vt);
    k_attn<<<dim3(4, HEADS, BATCH), 1024, ATTN_LDS_BYTES, stream>>>(Qb, Kb, Vt, out);
}